// Round 1
// baseline (1306.752 us; speedup 1.0000x reference)
//
#include <hip/hip_runtime.h>
#include <hip/hip_bf16.h>

#define BATCH 32
#define HW1 224

// ---------------------------------------------------------------------------
// Kernel A: generate dynamic conv weights (batch-invariant!), fold BN consts,
// zero the feat accumulator.
// ---------------------------------------------------------------------------
__global__ __launch_bounds__(256) void gen_params(
    const float* __restrict__ w1, const float* __restrict__ b1,
    const float* __restrict__ w2, const float* __restrict__ b2,
    const float* __restrict__ w3, const float* __restrict__ b3,
    const float* __restrict__ wb, const float* __restrict__ bb,
    const float* __restrict__ conv2_b, const float* __restrict__ conv3_b,
    const float* __restrict__ bn1_g, const float* __restrict__ bn1_b,
    const float* __restrict__ bn1_m, const float* __restrict__ bn1_v,
    const float* __restrict__ bn2_g, const float* __restrict__ bn2_b,
    const float* __restrict__ bn2_m, const float* __restrict__ bn2_v,
    const float* __restrict__ bn3_g, const float* __restrict__ bn3_b,
    const float* __restrict__ bn3_m, const float* __restrict__ bn3_v,
    float* __restrict__ dyn_w,
    float* __restrict__ bn1_s, float* __restrict__ bn1_t,
    float* __restrict__ bn2_s, float* __restrict__ bn2_t,
    float* __restrict__ bn3_s, float* __restrict__ bn3_t,
    float* __restrict__ feat)
{
    __shared__ float h1[128];
    __shared__ float h2[256];
    const int t = threadIdx.x;

    // h1 = relu(ones @ w1.T + b1)   (ind is all-ones since C == max_in_channels)
    if (t < 128) {
        float s = b1[t] + w1[t*3+0] + w1[t*3+1] + w1[t*3+2];
        h1[t] = fmaxf(s, 0.f);
    }
    __syncthreads();
    // h2 = relu(h1 @ w2.T + b2)
    {
        float s = b2[t];
        for (int k = 0; k < 128; ++k) s = fmaf(w2[t*128+k], h1[k], s);
        h2[t] = fmaxf(s, 0.f);
    }
    __syncthreads();
    // dyn_w = h2 @ w3.T + b3   (864 = 32*3*3*3)
    for (int i = t; i < 864; i += 256) {
        float s = b3[i];
        const float* wr = w3 + (size_t)i*256;
        for (int k = 0; k < 256; ++k) s = fmaf(wr[k], h2[k], s);
        dyn_w[i] = s;
    }
    // BN folds. bn: y = x*s + (bias - m)*s + b  with s = g/sqrt(v+eps)
    if (t < 32) {
        float dynb = bb[t] + wb[t*3+0] + wb[t*3+1] + wb[t*3+2];
        float s = bn1_g[t] / sqrtf(bn1_v[t] + 1e-5f);
        bn1_s[t] = s;
        bn1_t[t] = (dynb - bn1_m[t]) * s + bn1_b[t];
    }
    if (t < 64) {
        float s = bn2_g[t] / sqrtf(bn2_v[t] + 1e-5f);
        bn2_s[t] = s;
        bn2_t[t] = (conv2_b[t] - bn2_m[t]) * s + bn2_b[t];
    }
    if (t < 128) {
        float s = bn3_g[t] / sqrtf(bn3_v[t] + 1e-5f);
        bn3_s[t] = s;
        bn3_t[t] = (conv3_b[t] - bn3_m[t]) * s + bn3_b[t];
    }
    // zero feat accumulator (32*128)
    for (int i = t; i < BATCH*128; i += 256) feat[i] = 0.f;
}

// ---------------------------------------------------------------------------
// Kernel B: conv1 (3->32, 224x224, pad1) + bn + relu + 2x2 maxpool -> 112x112
// One block per (b, oc). Weights wave-uniform -> scalar loads.
// ---------------------------------------------------------------------------
__global__ __launch_bounds__(256) void conv1_pool(
    const float* __restrict__ x, const float* __restrict__ dw,
    const float* __restrict__ bn_s, const float* __restrict__ bn_t,
    float* __restrict__ out)
{
    const int b  = blockIdx.x >> 5;
    const int oc = blockIdx.x & 31;
    float w[27];
#pragma unroll
    for (int i = 0; i < 27; ++i) w[i] = dw[oc*27 + i];
    const float s = bn_s[oc], t = bn_t[oc];
    const float* xb = x + (size_t)b * 3 * HW1 * HW1;
    float* ob = out + ((size_t)(b*32 + oc)) * 112 * 112;

    for (int p = threadIdx.x; p < 112*112; p += 256) {
        int ph = p / 112, pw = p - ph*112;
        int y0 = 2*ph - 1, x0 = 2*pw - 1;
        float patch[3][4][4];
#pragma unroll
        for (int ic = 0; ic < 3; ++ic)
#pragma unroll
            for (int r = 0; r < 4; ++r) {
                int gy = y0 + r;
#pragma unroll
                for (int c = 0; c < 4; ++c) {
                    int gx = x0 + c;
                    patch[ic][r][c] =
                        ((unsigned)gy < HW1 && (unsigned)gx < HW1)
                            ? xb[(ic*HW1 + gy)*HW1 + gx] : 0.f;
                }
            }
        float vmax = 0.f;  // relu >= 0 so 0 is a safe identity
#pragma unroll
        for (int dy = 0; dy < 2; ++dy)
#pragma unroll
            for (int dx = 0; dx < 2; ++dx) {
                float conv = 0.f;
#pragma unroll
                for (int ic = 0; ic < 3; ++ic)
#pragma unroll
                    for (int ky = 0; ky < 3; ++ky)
#pragma unroll
                        for (int kx = 0; kx < 3; ++kx)
                            conv = fmaf(w[ic*9 + ky*3 + kx],
                                        patch[ic][dy+ky][dx+kx], conv);
                vmax = fmaxf(vmax, fmaxf(fmaf(conv, s, t), 0.f));
            }
        ob[p] = vmax;
    }
}

// ---------------------------------------------------------------------------
// Tiled direct conv template for conv2/conv3.
// Block: 256 threads = 16x16. Conv tile 32x32 (thread owns 2 rows x {tx,tx+16}
// cols = 4 pixels), OCT=16 out channels, ICC=4 input channels staged in LDS.
// POOL=true : bn+relu+2x2maxpool, write NCHW pooled output.
// POOL=false: bn+relu+spatial sum (for global mean), atomicAdd into feat[B,OC].
// ---------------------------------------------------------------------------
template<int ICTOT, int OCTOT, int HW, bool POOL>
__global__ __launch_bounds__(256) void conv_tiled(
    const float* __restrict__ in, const float* __restrict__ wt,
    const float* __restrict__ bn_s, const float* __restrict__ bn_t,
    float* __restrict__ out)
{
    constexpr int ICC = 4;
    constexpr int OCT = 16;
    constexpr int BX  = 16;
    constexpr int PS  = 36;   // padded LDS row stride (bank-conflict-free: 2-way max)

    __shared__ float sp[ICC*34*PS];
    __shared__ __align__(16) float sw[OCT*ICC*12];

    const int tid = threadIdx.x;
    const int tx = tid & 15, ty = tid >> 4;
    constexpr int nOcB = OCTOT / OCT;
    const int b   = blockIdx.z / nOcB;
    const int oc0 = (blockIdx.z % nOcB) * OCT;
    const int cy0 = blockIdx.y * 32, cx0 = blockIdx.x * 32;

    float acc[OCT][4];
#pragma unroll
    for (int o = 0; o < OCT; ++o)
#pragma unroll
        for (int p = 0; p < 4; ++p) acc[o][p] = 0.f;

    for (int ic0 = 0; ic0 < ICTOT; ic0 += ICC) {
        __syncthreads();
        // stage input patch (34x34 per ic, zero-padded at borders)
        for (int i = tid; i < ICC*34*34; i += 256) {
            int ic  = i / (34*34);
            int rem = i - ic*(34*34);
            int r = rem / 34, c = rem - r*34;
            int gy = cy0 - 1 + r, gx = cx0 - 1 + c;
            float v = 0.f;
            if ((unsigned)gy < HW && (unsigned)gx < HW)
                v = in[(((size_t)b*ICTOT + ic0 + ic)*HW + gy)*HW + gx];
            sp[(ic*34 + r)*PS + c] = v;
        }
        // stage weights (pad 9 -> 12 so each oc row is 16B aligned)
        for (int i = tid; i < OCT*ICC*9; i += 256) {
            int o   = i / (ICC*9);
            int rem = i - o*(ICC*9);
            int ic = rem / 9, k = rem - ic*9;
            sw[(o*ICC + ic)*12 + k] = wt[((size_t)(oc0+o)*ICTOT + ic0 + ic)*9 + k];
        }
        __syncthreads();

#pragma unroll
        for (int ic = 0; ic < ICC; ++ic) {
            float pL[4][3], pR[4][3];
            const float* pb = &sp[(ic*34 + 2*ty)*PS + tx];
#pragma unroll
            for (int r = 0; r < 4; ++r)
#pragma unroll
                for (int c = 0; c < 3; ++c) {
                    pL[r][c] = pb[r*PS + c];
                    pR[r][c] = pb[r*PS + BX + c];
                }
#pragma unroll
            for (int o = 0; o < OCT; ++o) {
                const float* wp = &sw[(o*ICC + ic)*12];
                float4 wa = *(const float4*)wp;
                float4 wbv = *(const float4*)(wp + 4);
                float wk[9] = {wa.x, wa.y, wa.z, wa.w,
                               wbv.x, wbv.y, wbv.z, wbv.w, wp[8]};
#pragma unroll
                for (int ky = 0; ky < 3; ++ky)
#pragma unroll
                    for (int kx = 0; kx < 3; ++kx) {
                        float wv = wk[ky*3 + kx];
                        acc[o][0] = fmaf(wv, pL[ky  ][kx], acc[o][0]);
                        acc[o][1] = fmaf(wv, pL[ky+1][kx], acc[o][1]);
                        acc[o][2] = fmaf(wv, pR[ky  ][kx], acc[o][2]);
                        acc[o][3] = fmaf(wv, pR[ky+1][kx], acc[o][3]);
                    }
            }
        }
    }

    if (POOL) {
        constexpr int OH = HW / 2;
#pragma unroll
        for (int o = 0; o < OCT; ++o) {
            float s = bn_s[oc0+o], t = bn_t[oc0+o];
            float v0 = fmaxf(fmaf(acc[o][0], s, t), 0.f);
            float v1 = fmaxf(fmaf(acc[o][1], s, t), 0.f);
            float v2 = fmaxf(fmaf(acc[o][2], s, t), 0.f);
            float v3 = fmaxf(fmaf(acc[o][3], s, t), 0.f);
            float vL = fmaxf(v0, v1);
            float vR = fmaxf(v2, v3);
            float oL = fmaxf(vL, __shfl_xor(vL, 1));
            float oR = fmaxf(vR, __shfl_xor(vR, 1));
            if ((tx & 1) == 0) {
                int py  = (cy0 >> 1) + ty;
                int pxL = (cx0 >> 1) + (tx >> 1);
                int pxR = pxL + (BX >> 1);
                if (py < OH) {
                    float* ob = out + (((size_t)b*OCTOT + oc0 + o)*OH + py)*OH;
                    if (pxL < OH) ob[pxL] = oL;
                    if (pxR < OH) ob[pxR] = oR;
                }
            }
        }
    } else {
#pragma unroll
        for (int o = 0; o < OCT; ++o) {
            float s = bn_s[oc0+o], t = bn_t[oc0+o];
            int cy = cy0 + 2*ty;
            int cxL = cx0 + tx, cxR = cxL + BX;
            bool y0ok = (cy < HW), y1ok = (cy + 1 < HW);
            float psum = 0.f;
            if (cxL < HW) {
                if (y0ok) psum += fmaxf(fmaf(acc[o][0], s, t), 0.f);
                if (y1ok) psum += fmaxf(fmaf(acc[o][1], s, t), 0.f);
            }
            if (cxR < HW) {
                if (y0ok) psum += fmaxf(fmaf(acc[o][2], s, t), 0.f);
                if (y1ok) psum += fmaxf(fmaf(acc[o][3], s, t), 0.f);
            }
#pragma unroll
            for (int m = 1; m < 64; m <<= 1) psum += __shfl_xor(psum, m);
            if ((tid & 63) == 0) atomicAdd(&out[b*OCTOT + oc0 + o], psum);
        }
    }
}

// ---------------------------------------------------------------------------
// Kernel E: FC head. out[b,n] = (feat_sum[b,:]/3136) @ fc_w[n,:] + fc_b[n]
// ---------------------------------------------------------------------------
__global__ __launch_bounds__(256) void fc_kernel(
    const float* __restrict__ feat, const float* __restrict__ fc_w,
    const float* __restrict__ fc_b, float* __restrict__ out)
{
    int i = blockIdx.x * 256 + threadIdx.x;
    if (i >= BATCH*100) return;
    int b = i / 100, n = i - b*100;
    const float* f = feat + b*128;
    const float* w = fc_w + n*128;
    float s = 0.f;
#pragma unroll 4
    for (int k = 0; k < 128; ++k) s = fmaf(f[k], w[k], s);
    out[i] = s * (1.f/3136.f) + fc_b[n];
}

extern "C" void kernel_launch(void* const* d_in, const int* in_sizes, int n_in,
                              void* d_out, int out_size, void* d_ws, size_t ws_size,
                              hipStream_t stream)
{
    const float* x       = (const float*)d_in[0];
    const float* w1      = (const float*)d_in[1];
    const float* b1      = (const float*)d_in[2];
    const float* w2      = (const float*)d_in[3];
    const float* b2      = (const float*)d_in[4];
    const float* w3      = (const float*)d_in[5];
    const float* b3      = (const float*)d_in[6];
    const float* wb      = (const float*)d_in[7];
    const float* bb      = (const float*)d_in[8];
    const float* conv2_w = (const float*)d_in[9];
    const float* conv2_b = (const float*)d_in[10];
    const float* conv3_w = (const float*)d_in[11];
    const float* conv3_b = (const float*)d_in[12];
    const float* bn1_g = (const float*)d_in[13];
    const float* bn1_b = (const float*)d_in[14];
    const float* bn1_m = (const float*)d_in[15];
    const float* bn1_v = (const float*)d_in[16];
    const float* bn2_g = (const float*)d_in[17];
    const float* bn2_b = (const float*)d_in[18];
    const float* bn2_m = (const float*)d_in[19];
    const float* bn2_v = (const float*)d_in[20];
    const float* bn3_g = (const float*)d_in[21];
    const float* bn3_b = (const float*)d_in[22];
    const float* bn3_m = (const float*)d_in[23];
    const float* bn3_v = (const float*)d_in[24];
    const float* fc_w  = (const float*)d_in[25];
    const float* fc_b  = (const float*)d_in[26];
    float* out = (float*)d_out;

    float* ws    = (float*)d_ws;
    float* dyn_w = ws;                  // 864
    float* bn1_s = ws + 864;            // 32
    float* bn1_t = ws + 896;            // 32
    float* bn2_s = ws + 928;            // 64
    float* bn2_t = ws + 992;            // 64
    float* bn3_s = ws + 1056;           // 128
    float* bn3_t = ws + 1184;           // 128
    float* feat  = ws + 1312;           // 32*128 = 4096
    float* pool1 = ws + 8192;           // 32*32*112*112 = 12845056 floats
    float* pool2 = pool1 + 12845056;    // 32*64*56*56  = 6422528 floats

    gen_params<<<1, 256, 0, stream>>>(
        w1, b1, w2, b2, w3, b3, wb, bb, conv2_b, conv3_b,
        bn1_g, bn1_b, bn1_m, bn1_v, bn2_g, bn2_b, bn2_m, bn2_v,
        bn3_g, bn3_b, bn3_m, bn3_v,
        dyn_w, bn1_s, bn1_t, bn2_s, bn2_t, bn3_s, bn3_t, feat);

    conv1_pool<<<BATCH*32, 256, 0, stream>>>(x, dyn_w, bn1_s, bn1_t, pool1);

    dim3 g2(4, 4, BATCH * (64/16));   // 112/32 -> 4 tiles (masked), 4 oc blocks
    conv_tiled<32, 64, 112, true><<<g2, 256, 0, stream>>>(
        pool1, conv2_w, bn2_s, bn2_t, pool2);

    dim3 g3(2, 2, BATCH * (128/16));  // 56/32 -> 2 tiles (masked), 8 oc blocks
    conv_tiled<64, 128, 56, false><<<g3, 256, 0, stream>>>(
        pool2, conv3_w, bn3_s, bn3_t, feat);

    fc_kernel<<<(BATCH*100 + 255)/256, 256, 0, stream>>>(feat, fc_w, fc_b, out);
}

// Round 2
// 263.966 us; speedup vs baseline: 4.9505x; 4.9505x over previous
//
#include <hip/hip_runtime.h>
#include <hip/hip_bf16.h>

#define BATCH 32
#define HW1 224

typedef __attribute__((ext_vector_type(8))) short short8;
typedef __attribute__((ext_vector_type(4))) float floatx4;

static __device__ __forceinline__ unsigned short f2bf(float f) {
    unsigned int u = __float_as_uint(f);
    unsigned int r = (u + 0x7fffu + ((u >> 16) & 1u)) >> 16;   // RNE
    return (unsigned short)r;
}

// ---------------------------------------------------------------------------
// Kernel A: generate dynamic conv weights (batch-invariant), fold BN consts,
// zero the feat accumulator.
// ---------------------------------------------------------------------------
__global__ __launch_bounds__(256) void gen_params(
    const float* __restrict__ w1, const float* __restrict__ b1,
    const float* __restrict__ w2, const float* __restrict__ b2,
    const float* __restrict__ w3, const float* __restrict__ b3,
    const float* __restrict__ wb, const float* __restrict__ bb,
    const float* __restrict__ conv2_b, const float* __restrict__ conv3_b,
    const float* __restrict__ bn1_g, const float* __restrict__ bn1_b,
    const float* __restrict__ bn1_m, const float* __restrict__ bn1_v,
    const float* __restrict__ bn2_g, const float* __restrict__ bn2_b,
    const float* __restrict__ bn2_m, const float* __restrict__ bn2_v,
    const float* __restrict__ bn3_g, const float* __restrict__ bn3_b,
    const float* __restrict__ bn3_m, const float* __restrict__ bn3_v,
    float* __restrict__ dyn_w,
    float* __restrict__ bn1_s, float* __restrict__ bn1_t,
    float* __restrict__ bn2_s, float* __restrict__ bn2_t,
    float* __restrict__ bn3_s, float* __restrict__ bn3_t,
    float* __restrict__ feat)
{
    __shared__ float h1[128];
    __shared__ float h2[256];
    const int t = threadIdx.x;

    if (t < 128) {
        float s = b1[t] + w1[t*3+0] + w1[t*3+1] + w1[t*3+2];
        h1[t] = fmaxf(s, 0.f);
    }
    __syncthreads();
    {
        float s = b2[t];
        for (int k = 0; k < 128; ++k) s = fmaf(w2[t*128+k], h1[k], s);
        h2[t] = fmaxf(s, 0.f);
    }
    __syncthreads();
    for (int i = t; i < 864; i += 256) {
        float s = b3[i];
        const float* wr = w3 + (size_t)i*256;
        for (int k = 0; k < 256; ++k) s = fmaf(wr[k], h2[k], s);
        dyn_w[i] = s;
    }
    if (t < 32) {
        float dynb = bb[t] + wb[t*3+0] + wb[t*3+1] + wb[t*3+2];
        float s = bn1_g[t] / sqrtf(bn1_v[t] + 1e-5f);
        bn1_s[t] = s;
        bn1_t[t] = (dynb - bn1_m[t]) * s + bn1_b[t];
    }
    if (t < 64) {
        float s = bn2_g[t] / sqrtf(bn2_v[t] + 1e-5f);
        bn2_s[t] = s;
        bn2_t[t] = (conv2_b[t] - bn2_m[t]) * s + bn2_b[t];
    }
    if (t < 128) {
        float s = bn3_g[t] / sqrtf(bn3_v[t] + 1e-5f);
        bn3_s[t] = s;
        bn3_t[t] = (conv3_b[t] - bn3_m[t]) * s + bn3_b[t];
    }
    for (int i = t; i < BATCH*128; i += 256) feat[i] = 0.f;
}

// ---------------------------------------------------------------------------
// Kernel A2: repack conv2_w/conv3_w [OC][IC][3][3] fp32 -> [tap][OC][IC] bf16
// so MFMA A-fragments are contiguous 16B (8 ic) loads.
// ---------------------------------------------------------------------------
__global__ __launch_bounds__(256) void repack_w(
    const float* __restrict__ conv2_w, const float* __restrict__ conv3_w,
    unsigned short* __restrict__ wrep2, unsigned short* __restrict__ wrep3)
{
    int i = blockIdx.x * 256 + threadIdx.x;
    const int N2 = 9*64*32;   // 18432
    const int N3 = 9*128*64;  // 73728
    if (i < N2) {
        int t = i / (64*32); int rem = i - t*(64*32);
        int oc = rem >> 5, ic = rem & 31;
        wrep2[i] = f2bf(conv2_w[(oc*32 + ic)*9 + t]);
    } else if (i < N2 + N3) {
        int j = i - N2;
        int t = j / (128*64); int rem = j - t*(128*64);
        int oc = rem >> 6, ic = rem & 63;
        wrep3[j] = f2bf(conv3_w[(oc*64 + ic)*9 + t]);
    }
}

// ---------------------------------------------------------------------------
// Kernel B: conv1 (3->32, 224x224, pad1) + bn + relu + 2x2 maxpool.
// Output: bf16 channel-last act1[b][112][112][32].
// Block = pooled 16x16 tile x 16 oc (z = b*2 + oc_half). Input tile in LDS.
// ---------------------------------------------------------------------------
__global__ __launch_bounds__(256) void conv1_pool(
    const float* __restrict__ x, const float* __restrict__ dw,
    const float* __restrict__ bn_s, const float* __restrict__ bn_t,
    unsigned short* __restrict__ act1)
{
    constexpr int PS = 37;                 // padded LDS row stride (floats)
    __shared__ __align__(16) float sp[3*34*PS];
    __shared__ __align__(16) float swt[16*28];

    const int tid = threadIdx.x;
    const int bx = blockIdx.x, by = blockIdx.y;
    const int b  = blockIdx.z >> 1, h = blockIdx.z & 1;
    const int gx0 = bx*32 - 1, gy0 = by*32 - 1;
    const float* xb = x + (size_t)b * 3 * HW1 * HW1;

    for (int i = tid; i < 3*34*34; i += 256) {
        int ch = i / 1156; int rem = i - ch*1156;
        int r = rem / 34, c = rem - r*34;
        int gy = gy0 + r, gx = gx0 + c;
        float v = 0.f;
        if ((unsigned)gy < HW1 && (unsigned)gx < HW1)
            v = xb[(ch*HW1 + gy)*HW1 + gx];
        sp[(ch*34 + r)*PS + c] = v;
    }
    for (int i = tid; i < 16*27; i += 256) {
        int oc = i / 27, k = i - oc*27;
        swt[oc*28 + k] = dw[(h*16 + oc)*27 + k];
    }
    __syncthreads();

    const int tx = tid & 15, ty = tid >> 4;
    float p[3][4][4];
#pragma unroll
    for (int ch = 0; ch < 3; ++ch)
#pragma unroll
        for (int r = 0; r < 4; ++r)
#pragma unroll
            for (int c = 0; c < 4; ++c)
                p[ch][r][c] = sp[(ch*34 + 2*ty + r)*PS + 2*tx + c];

    unsigned int packed[8];
#pragma unroll
    for (int oc = 0; oc < 16; ++oc) {
        float wk[28];
#pragma unroll
        for (int q = 0; q < 7; ++q)
            *(float4*)&wk[q*4] = *(const float4*)&swt[oc*28 + q*4];
        float bs = bn_s[h*16 + oc], bt = bn_t[h*16 + oc];
        float vm = 0.f;   // relu >= 0
#pragma unroll
        for (int dy = 0; dy < 2; ++dy)
#pragma unroll
            for (int dx = 0; dx < 2; ++dx) {
                float conv = 0.f;
#pragma unroll
                for (int ch = 0; ch < 3; ++ch)
#pragma unroll
                    for (int ky = 0; ky < 3; ++ky)
#pragma unroll
                        for (int kx = 0; kx < 3; ++kx)
                            conv = fmaf(wk[ch*9 + ky*3 + kx],
                                        p[ch][dy+ky][dx+kx], conv);
                vm = fmaxf(vm, fmaxf(fmaf(conv, bs, bt), 0.f));
            }
        unsigned short us = f2bf(vm);
        if (oc & 1) packed[oc >> 1] |= ((unsigned int)us) << 16;
        else        packed[oc >> 1]  = us;
    }
    int py = by*16 + ty, px = bx*16 + tx;
    unsigned short* dst = act1 + ((size_t)((b*112 + py)*112 + px))*32 + h*16;
    *(uint4*)(dst)     = *(uint4*)&packed[0];
    *(uint4*)(dst + 8) = *(uint4*)&packed[4];
}

// ---------------------------------------------------------------------------
// Kernel C: conv2 (32->64, 112x112) bf16 MFMA + bn + relu + 2x2 maxpool.
// Shifted-GEMM: out[oc,pix] = sum_tap W[tap][oc][:] . act[pix+tap][:]
// A = weights (regs, 9 frags), B = pixels from LDS (chunked channel-last).
// Block = 16x16 pixel tile, 4 waves x 16 oc = all 64 oc. One stage, one sync.
// Output: bf16 channel-last act2[b][56][56][64].
// ---------------------------------------------------------------------------
__global__ __launch_bounds__(256) void conv2_mfma(
    const unsigned short* __restrict__ act1,
    const unsigned short* __restrict__ wrep,
    const float* __restrict__ bn_s, const float* __restrict__ bn_t,
    unsigned short* __restrict__ act2)
{
    constexpr int IC = 32, OC = 64, H = 112;
    __shared__ __align__(16) short lds[4*18*18*8];   // [chunk][y][x][8ic] 20.7KB

    const int tid = threadIdx.x;
    const int b = blockIdx.z;
    const int cx0 = blockIdx.x*16, cy0 = blockIdx.y*16;
    const unsigned short* ab = act1 + (size_t)b*H*H*IC;

    for (int s = tid; s < 4*324; s += 256) {
        int ck = s / 324; int rem = s - ck*324;
        int y = rem / 18, xx = rem - y*18;
        int gy = cy0 - 1 + y, gx = cx0 - 1 + xx;
        uint4 v = {0,0,0,0};
        if ((unsigned)gy < H && (unsigned)gx < H)
            v = *(const uint4*)(ab + (size_t)(gy*H + gx)*IC + ck*8);
        *(uint4*)&lds[s*8] = v;
    }

    const int lane = tid & 63, wave = tid >> 6;
    const int n = lane & 15, quad = lane >> 4;
    const int oc0w = wave * 16;

    short8 afr[9];
#pragma unroll
    for (int t = 0; t < 9; ++t)
        afr[t] = *(const short8*)(wrep + (size_t)(t*OC + oc0w + n)*IC + quad*8);

    float4 sv = *(const float4*)(bn_s + oc0w + quad*4);
    float4 tv = *(const float4*)(bn_t + oc0w + quad*4);

    __syncthreads();

    for (int ry = 0; ry < 8; ++ry) {
        floatx4 acc0 = {0.f,0.f,0.f,0.f};
        floatx4 acc1 = {0.f,0.f,0.f,0.f};
        int y0 = 2*ry;
#pragma unroll
        for (int ky = 0; ky < 3; ++ky)
#pragma unroll
            for (int kx = 0; kx < 3; ++kx) {
                int t = ky*3 + kx;
                short8 b0 = *(const short8*)&lds[((quad*18 + y0+ky  )*18 + n+kx)*8];
                short8 b1 = *(const short8*)&lds[((quad*18 + y0+1+ky)*18 + n+kx)*8];
                acc0 = __builtin_amdgcn_mfma_f32_16x16x32_bf16(afr[t], b0, acc0, 0, 0, 0);
                acc1 = __builtin_amdgcn_mfma_f32_16x16x32_bf16(afr[t], b1, acc1, 0, 0, 0);
            }
        // bn + relu + 2x2 pool (rows in-lane, cols via shfl) + bf16 pack
        unsigned int pk[2];
        float sj[4] = {sv.x, sv.y, sv.z, sv.w};
        float tj[4] = {tv.x, tv.y, tv.z, tv.w};
#pragma unroll
        for (int j = 0; j < 4; ++j) {
            float va = fmaxf(fmaf(acc0[j], sj[j], tj[j]), 0.f);
            float vb = fmaxf(fmaf(acc1[j], sj[j], tj[j]), 0.f);
            float m  = fmaxf(va, vb);
            m = fmaxf(m, __shfl_xor(m, 1));
            unsigned short us = f2bf(m);
            if (j & 1) pk[j >> 1] |= ((unsigned int)us) << 16;
            else       pk[j >> 1]  = us;
        }
        if (!(n & 1)) {
            int py = (cy0 >> 1) + ry, px = (cx0 >> 1) + (n >> 1);
            unsigned short* dst = act2 + ((size_t)((b*56 + py)*56 + px))*OC + oc0w + quad*4;
            *(uint2*)dst = *(uint2*)pk;
        }
    }
}

// ---------------------------------------------------------------------------
// Kernel D: conv3 (64->128, 56x56) bf16 MFMA + bn + relu + spatial mean sum.
// Same structure, K=64 (2 chunks of 32), no pool; atomicAdd into feat[B,128].
// ---------------------------------------------------------------------------
__global__ __launch_bounds__(256) void conv3_mfma(
    const unsigned short* __restrict__ act2,
    const unsigned short* __restrict__ wrep,
    const float* __restrict__ bn_s, const float* __restrict__ bn_t,
    float* __restrict__ feat)
{
    constexpr int IC = 64, OC = 128, H = 56;
    __shared__ __align__(16) short lds[8*18*18*8];   // 41.5KB

    const int tid = threadIdx.x;
    const int b = blockIdx.z >> 1, half = blockIdx.z & 1;
    const int cx0 = blockIdx.x*16, cy0 = blockIdx.y*16;
    const unsigned short* ab = act2 + (size_t)b*H*H*IC;

    for (int s = tid; s < 8*324; s += 256) {
        int ck = s / 324; int rem = s - ck*324;
        int y = rem / 18, xx = rem - y*18;
        int gy = cy0 - 1 + y, gx = cx0 - 1 + xx;
        uint4 v = {0,0,0,0};
        if ((unsigned)gy < H && (unsigned)gx < H)
            v = *(const uint4*)(ab + (size_t)(gy*H + gx)*IC + ck*8);
        *(uint4*)&lds[s*8] = v;
    }

    const int lane = tid & 63, wave = tid >> 6;
    const int n = lane & 15, quad = lane >> 4;
    const int oc0w = half*64 + wave*16;

    short8 afr[18];   // [tap][kc]
#pragma unroll
    for (int t = 0; t < 9; ++t)
#pragma unroll
        for (int kc = 0; kc < 2; ++kc)
            afr[t*2 + kc] = *(const short8*)(wrep + (size_t)(t*OC + oc0w + n)*IC + kc*32 + quad*8);

    float4 sv = *(const float4*)(bn_s + oc0w + quad*4);
    float4 tv = *(const float4*)(bn_t + oc0w + quad*4);

    __syncthreads();

    float sum[4] = {0.f, 0.f, 0.f, 0.f};
    const bool vx = (cx0 + n) < H;
    const int ymax = (H - cy0) < 16 ? (H - cy0) : 16;
    float sj[4] = {sv.x, sv.y, sv.z, sv.w};
    float tj[4] = {tv.x, tv.y, tv.z, tv.w};

    for (int y = 0; y < ymax; ++y) {
        floatx4 acc0 = {0.f,0.f,0.f,0.f};   // kc=0 chain
        floatx4 acc1 = {0.f,0.f,0.f,0.f};   // kc=1 chain
#pragma unroll
        for (int ky = 0; ky < 3; ++ky)
#pragma unroll
            for (int kx = 0; kx < 3; ++kx) {
                int t = ky*3 + kx;
                short8 b0 = *(const short8*)&lds[(((0*4 + quad)*18 + y+ky)*18 + n+kx)*8];
                short8 b1 = *(const short8*)&lds[(((1*4 + quad)*18 + y+ky)*18 + n+kx)*8];
                acc0 = __builtin_amdgcn_mfma_f32_16x16x32_bf16(afr[t*2+0], b0, acc0, 0, 0, 0);
                acc1 = __builtin_amdgcn_mfma_f32_16x16x32_bf16(afr[t*2+1], b1, acc1, 0, 0, 0);
            }
        if (vx) {
#pragma unroll
            for (int j = 0; j < 4; ++j)
                sum[j] += fmaxf(fmaf(acc0[j] + acc1[j], sj[j], tj[j]), 0.f);
        }
    }
#pragma unroll
    for (int j = 0; j < 4; ++j) {
        sum[j] += __shfl_xor(sum[j], 1);
        sum[j] += __shfl_xor(sum[j], 2);
        sum[j] += __shfl_xor(sum[j], 4);
        sum[j] += __shfl_xor(sum[j], 8);
    }
    if (n == 0) {
#pragma unroll
        for (int j = 0; j < 4; ++j)
            atomicAdd(&feat[b*128 + oc0w + quad*4 + j], sum[j]);
    }
}

// ---------------------------------------------------------------------------
// Kernel E: FC head. out[b,n] = (feat_sum[b,:]/3136) @ fc_w[n,:] + fc_b[n]
// ---------------------------------------------------------------------------
__global__ __launch_bounds__(256) void fc_kernel(
    const float* __restrict__ feat, const float* __restrict__ fc_w,
    const float* __restrict__ fc_b, float* __restrict__ out)
{
    int i = blockIdx.x * 256 + threadIdx.x;
    if (i >= BATCH*100) return;
    int b = i / 100, n = i - b*100;
    const float* f = feat + b*128;
    const float* w = fc_w + n*128;
    float s = 0.f;
#pragma unroll 4
    for (int k = 0; k < 128; ++k) s = fmaf(f[k], w[k], s);
    out[i] = s * (1.f/3136.f) + fc_b[n];
}

extern "C" void kernel_launch(void* const* d_in, const int* in_sizes, int n_in,
                              void* d_out, int out_size, void* d_ws, size_t ws_size,
                              hipStream_t stream)
{
    const float* x       = (const float*)d_in[0];
    const float* w1      = (const float*)d_in[1];
    const float* b1      = (const float*)d_in[2];
    const float* w2      = (const float*)d_in[3];
    const float* b2      = (const float*)d_in[4];
    const float* w3      = (const float*)d_in[5];
    const float* b3      = (const float*)d_in[6];
    const float* wb      = (const float*)d_in[7];
    const float* bb      = (const float*)d_in[8];
    const float* conv2_w = (const float*)d_in[9];
    const float* conv2_b = (const float*)d_in[10];
    const float* conv3_w = (const float*)d_in[11];
    const float* conv3_b = (const float*)d_in[12];
    const float* bn1_g = (const float*)d_in[13];
    const float* bn1_b = (const float*)d_in[14];
    const float* bn1_m = (const float*)d_in[15];
    const float* bn1_v = (const float*)d_in[16];
    const float* bn2_g = (const float*)d_in[17];
    const float* bn2_b = (const float*)d_in[18];
    const float* bn2_m = (const float*)d_in[19];
    const float* bn2_v = (const float*)d_in[20];
    const float* bn3_g = (const float*)d_in[21];
    const float* bn3_b = (const float*)d_in[22];
    const float* bn3_m = (const float*)d_in[23];
    const float* bn3_v = (const float*)d_in[24];
    const float* fc_w  = (const float*)d_in[25];
    const float* fc_b  = (const float*)d_in[26];
    float* out = (float*)d_out;

    // workspace layout (bytes)
    char* wsb = (char*)d_ws;
    float* ws    = (float*)d_ws;
    float* dyn_w = ws;                  // 864 f
    float* bn1_s = ws + 864;
    float* bn1_t = ws + 896;
    float* bn2_s = ws + 928;
    float* bn2_t = ws + 992;
    float* bn3_s = ws + 1056;
    float* bn3_t = ws + 1184;
    float* feat  = ws + 1312;           // 4096 f
    unsigned short* wrep2 = (unsigned short*)(wsb + 32768);    // 18432 ush
    unsigned short* wrep3 = (unsigned short*)(wsb + 69632);    // 73728 ush
    unsigned short* act1  = (unsigned short*)(wsb + 262144);   // 32*112*112*32 = 25.7MB
    unsigned short* act2  = (unsigned short*)(wsb + 262144 + 25690112); // 12.8MB

    gen_params<<<1, 256, 0, stream>>>(
        w1, b1, w2, b2, w3, b3, wb, bb, conv2_b, conv3_b,
        bn1_g, bn1_b, bn1_m, bn1_v, bn2_g, bn2_b, bn2_m, bn2_v,
        bn3_g, bn3_b, bn3_m, bn3_v,
        dyn_w, bn1_s, bn1_t, bn2_s, bn2_t, bn3_s, bn3_t, feat);

    repack_w<<<(9*64*32 + 9*128*64 + 255)/256, 256, 0, stream>>>(
        conv2_w, conv3_w, wrep2, wrep3);

    conv1_pool<<<dim3(7, 7, BATCH*2), 256, 0, stream>>>(
        x, dyn_w, bn1_s, bn1_t, act1);

    conv2_mfma<<<dim3(7, 7, BATCH), 256, 0, stream>>>(
        act1, wrep2, bn2_s, bn2_t, act2);

    conv3_mfma<<<dim3(4, 4, BATCH*2), 256, 0, stream>>>(
        act2, wrep3, bn3_s, bn3_t, feat);

    fc_kernel<<<(BATCH*100 + 255)/256, 256, 0, stream>>>(feat, fc_w, fc_b, out);
}